// Round 6
// baseline (432.084 us; speedup 1.0000x reference)
//
#include <hip/hip_runtime.h>
#include <hip/hip_bf16.h>

#define H 16
#define S 2048
#define DM 1024
#define HD 64
#define NB 2
#define LOG2E 1.4426950408889634f

typedef __attribute__((ext_vector_type(8))) short short8_t;
typedef __attribute__((ext_vector_type(4))) float f32x4;
typedef __attribute__((ext_vector_type(16))) float f32x16;

static __device__ __forceinline__ unsigned short f2bf(float f){
  union { float f; unsigned u; } x; x.f = f;
  unsigned r = x.u + 0x7fffu + ((x.u >> 16) & 1u);
  return (unsigned short)(r >> 16);
}

static __device__ __forceinline__ unsigned pk2(float a, float b){
  union { __hip_bfloat16 h; unsigned short u; } x, y;
  x.h = __hip_bfloat16(a); y.h = __hip_bfloat16(b);
  return (unsigned)x.u | ((unsigned)y.u << 16);
}

static __device__ __forceinline__ float ex2(float x){
#if __has_builtin(__builtin_amdgcn_exp2f)
  return __builtin_amdgcn_exp2f(x);
#else
  return exp2f(x);
#endif
}

// swap upper 32 lanes of x with lower 32 lanes of y (CDNA4 v_permlane32_swap_b32)
static __device__ __forceinline__ void pswap(unsigned &x, unsigned &y){
#if defined(__gfx950__) || defined(__AMDGCN__)
  asm("v_permlane32_swap_b32 %0, %1" : "+v"(x), "+v"(y));
#else
  unsigned sx = (unsigned)__shfl_xor((int)x, 32);
  unsigned sy = (unsigned)__shfl_xor((int)y, 32);
  bool hi = (threadIdx.x & 63) >= 32;
  unsigned nx = hi ? sy : x;
  unsigned ny = hi ? y : sx;
  x = nx; y = ny;
#endif
}

// ---------------- prep: all conversions in one launch ----------------
// blocks [0,6144): q/k/v fp32->bf16 (8 elems/thread)
// blocks [6144,8192): mask -> bitmask u16 (16 ints/thread)
// blocks [8192,12288): 4x weight transpose+convert (32x32 tiles)
__global__ __launch_bounds__(256) void prep(const float* __restrict__ q, const float* __restrict__ k,
    const float* __restrict__ v, const int* __restrict__ mask,
    const float* __restrict__ Wq, const float* __restrict__ Wk, const float* __restrict__ Wv,
    const float* __restrict__ Wo,
    unsigned short* __restrict__ qb, unsigned short* __restrict__ kb, unsigned short* __restrict__ vb,
    unsigned short* __restrict__ WT, unsigned short* __restrict__ WoT,
    unsigned short* __restrict__ m16){
  __shared__ float tt[32][33];
  const int bid = blockIdx.x, tid = threadIdx.x;
  if (bid < 6144){
    const int w = bid >> 11;
    const int blk = bid & 2047;
    const float* src = (w==0)? q : (w==1)? k : v;
    unsigned short* dst = (w==0)? qb : (w==1)? kb : vb;
    size_t i = ((size_t)blk*256 + tid)*8;
    float4 x = *(const float4*)(src + i);
    float4 y = *(const float4*)(src + i + 4);
    ushort4 o1{f2bf(x.x),f2bf(x.y),f2bf(x.z),f2bf(x.w)};
    ushort4 o2{f2bf(y.x),f2bf(y.y),f2bf(y.z),f2bf(y.w)};
    *(ushort4*)(dst+i) = o1; *(ushort4*)(dst+i+4) = o2;
  } else if (bid < 8192){
    size_t base = ((size_t)(bid-6144)*256 + tid)*16;
    unsigned u = 0;
    #pragma unroll
    for (int j2=0;j2<4;j2++){
      int4 mm = *(const int4*)(mask + base + j2*4);
      u |= (mm.x!=0 ? 1u:0u) << (j2*4);
      u |= (mm.y!=0 ? 1u:0u) << (j2*4+1);
      u |= (mm.z!=0 ? 1u:0u) << (j2*4+2);
      u |= (mm.w!=0 ? 1u:0u) << (j2*4+3);
    }
    m16[base>>4] = (unsigned short)u;
  } else {
    const int wb = bid - 8192;
    const int widx = wb >> 10, t = wb & 1023;
    const float* W = (widx==0)? Wq : (widx==1)? Wk : (widx==2)? Wv : Wo;
    unsigned short* dst = (widx<3)? (WT + (size_t)widx*DM*DM) : WoT;
    const int tx = tid & 31, ty = tid >> 5;
    const int r0 = (t >> 5) * 32, c0 = (t & 31) * 32;
    #pragma unroll
    for (int i2=0;i2<32;i2+=8) tt[ty+i2][tx] = W[(size_t)(r0+ty+i2)*DM + c0+tx];
    __syncthreads();
    #pragma unroll
    for (int i2=0;i2<32;i2+=8) dst[(size_t)(c0+ty+i2)*DM + r0+tx] = f2bf(tt[tx][ty+i2]);
  }
}

// ---------------- fused QKV GEMM: 2-deep reg pipeline ----------------
// 128x128 tile, BK=32, 4 waves (2x2). grid (24,32): p=blockIdx.x>>3 selects {Q,K,V}.
// Two staging reg sets (A=even tiles, B=odd): each ds_write consumes loads issued
// two compute-phases earlier -> compiler emits counted vmcnt, loads stay in flight.
__global__ __launch_bounds__(256, 3) void qkv_gemm(
    const unsigned short* __restrict__ qb, const unsigned short* __restrict__ kb,
    const unsigned short* __restrict__ vb2, const unsigned short* __restrict__ WT,
    const float* __restrict__ bq, const float* __restrict__ bk, const float* __restrict__ bv,
    unsigned short* __restrict__ Qp, unsigned short* __restrict__ Kp, unsigned short* __restrict__ VTp){
  __shared__ __align__(16) char Al[2][8192];
  __shared__ __align__(16) char Bl[2][8192];
  const int tid = threadIdx.x, lane = tid & 63, wv = tid >> 6;
  const int l15 = lane & 15, l4 = lane >> 4;
  const int wr = wv >> 1, wc = wv & 1;
  const int p = blockIdx.x >> 3;
  const int n0 = (blockIdx.x & 7) * 128;
  const int m0 = blockIdx.y * 128;
  const unsigned short* A = (p==0)? qb : (p==1)? kb : vb2;
  const unsigned short* Bt = WT + (size_t)blockIdx.x * 128 * DM;
  const float* bias = (p==0)? bq : (p==1)? bk : bv;
  const bool sw = (p==2);

  f32x4 acc[4][4];
  #pragma unroll
  for (int i=0;i<4;i++)
    #pragma unroll
    for (int j=0;j<4;j++) acc[i][j] = (f32x4){0.f,0.f,0.f,0.f};

  // unit u (c=u>>6, l=u&63): row = c*16 + (l&15), k8 = l>>4; LDS offset = u*16 (linear)
  const char *ga0, *ga1, *gb0, *gb1;
  {
    int u = tid, c = u>>6, l = u&63;
    ga0 = (const char*)A  + ((size_t)(m0 + c*16 + (l&15))*DM + (l>>4)*8)*2;
    gb0 = (const char*)Bt + ((size_t)(c*16 + (l&15))*DM + (l>>4)*8)*2;
    u = tid + 256; c = u>>6; l = u&63;
    ga1 = (const char*)A  + ((size_t)(m0 + c*16 + (l&15))*DM + (l>>4)*8)*2;
    gb1 = (const char*)Bt + ((size_t)(c*16 + (l&15))*DM + (l>>4)*8)*2;
  }
  const int lo0 = tid*16, lo1 = tid*16 + 4096;

  auto compute = [&](const char* __restrict__ Ab, const char* __restrict__ Bb){
    short8_t av[4], bvv[4];
    #pragma unroll
    for (int i=0;i<4;i++) av[i]  = *(const short8_t*)(Ab + (wr*4+i)*1024 + lane*16);
    #pragma unroll
    for (int j=0;j<4;j++) bvv[j] = *(const short8_t*)(Bb + (wc*4+j)*1024 + lane*16);
    __builtin_amdgcn_s_setprio(1);
    if (sw){
      #pragma unroll
      for (int i=0;i<4;i++)
        #pragma unroll
        for (int j=0;j<4;j++)
          acc[i][j] = __builtin_amdgcn_mfma_f32_16x16x32_bf16(bvv[j], av[i], acc[i][j], 0,0,0);
    } else {
      #pragma unroll
      for (int i=0;i<4;i++)
        #pragma unroll
        for (int j=0;j<4;j++)
          acc[i][j] = __builtin_amdgcn_mfma_f32_16x16x32_bf16(av[i], bvv[j], acc[i][j], 0,0,0);
    }
    __builtin_amdgcn_s_setprio(0);
  };

  const int NT = DM/32;   // 32
  uint4 Aa0,Aa1,Ab0,Ab1, Ba0,Ba1,Bb0,Bb1;
  // prologue: A <- tile0, B <- tile1, LDS0 <- A, A <- tile2
  Aa0=*(const uint4*)(ga0);     Aa1=*(const uint4*)(ga1);
  Ab0=*(const uint4*)(gb0);     Ab1=*(const uint4*)(gb1);
  Ba0=*(const uint4*)(ga0+64);  Ba1=*(const uint4*)(ga1+64);
  Bb0=*(const uint4*)(gb0+64);  Bb1=*(const uint4*)(gb1+64);
  *(uint4*)(Al[0]+lo0)=Aa0; *(uint4*)(Al[0]+lo1)=Aa1;
  *(uint4*)(Bl[0]+lo0)=Ab0; *(uint4*)(Bl[0]+lo1)=Ab1;
  Aa0=*(const uint4*)(ga0+128); Aa1=*(const uint4*)(ga1+128);
  Ab0=*(const uint4*)(gb0+128); Ab1=*(const uint4*)(gb1+128);
  __syncthreads();

  for (int u=0; u<NT/2; ++u){
    // tile 2u from buf0; write tile 2u+1 (set B) into buf1; reload B <- 2u+3
    compute(Al[0], Bl[0]);
    *(uint4*)(Al[1]+lo0)=Ba0; *(uint4*)(Al[1]+lo1)=Ba1;
    *(uint4*)(Bl[1]+lo0)=Bb0; *(uint4*)(Bl[1]+lo1)=Bb1;
    if (2*u+3 < NT){
      size_t o = (size_t)(2*u+3)*64;
      Ba0=*(const uint4*)(ga0+o); Ba1=*(const uint4*)(ga1+o);
      Bb0=*(const uint4*)(gb0+o); Bb1=*(const uint4*)(gb1+o);
    }
    __syncthreads();
    // tile 2u+1 from buf1; write tile 2u+2 (set A) into buf0; reload A <- 2u+4
    compute(Al[1], Bl[1]);
    if (2*u+2 < NT){
      *(uint4*)(Al[0]+lo0)=Aa0; *(uint4*)(Al[0]+lo1)=Aa1;
      *(uint4*)(Bl[0]+lo0)=Ab0; *(uint4*)(Bl[0]+lo1)=Ab1;
      if (2*u+4 < NT){
        size_t o = (size_t)(2*u+4)*64;
        Aa0=*(const uint4*)(ga0+o); Aa1=*(const uint4*)(ga1+o);
        Ab0=*(const uint4*)(gb0+o); Ab1=*(const uint4*)(gb1+o);
      }
    }
    __syncthreads();
  }

  if (!sw){
    unsigned short* out = (p==0)? Qp : Kp;
    const float scl = (p==0)? 0.125f*LOG2E : 1.0f;
    #pragma unroll
    for (int i=0;i<4;i++)
      #pragma unroll
      for (int j=0;j<4;j++)
        #pragma unroll
        for (int jr=0;jr<4;jr++){
          int m = m0 + wr*64 + i*16 + l4*4 + jr;
          int n = n0 + wc*64 + j*16 + l15;
          float val = (acc[i][j][jr] + bias[n]) * scl;
          int b2 = m >> 11, s = m & (S-1), hh2 = n >> 6, d = n & 63;
          out[(((size_t)b2*H + hh2)*S + s)*HD + d] = f2bf(val);
        }
  } else {
    #pragma unroll
    for (int i=0;i<4;i++)
      #pragma unroll
      for (int j=0;j<4;j++)
        #pragma unroll
        for (int jr=0;jr<4;jr++){
          int n = n0 + wc*64 + j*16 + l4*4 + jr;
          int m = m0 + wr*64 + i*16 + l15;
          float val = acc[i][j][jr] + bias[n];
          int b2 = m >> 11, s = m & (S-1), hh2 = n >> 6, d = n & 63;
          VTp[(((size_t)b2*H + hh2)*HD + d)*S + s] = f2bf(val);
        }
  }
}

// ---------------- output GEMM: 128x64 tile, 2-deep reg pipeline, fp32 out ----------------
__global__ __launch_bounds__(256, 2) void out_gemm(const unsigned short* __restrict__ A,
    const unsigned short* __restrict__ WoT, const float* __restrict__ bo, float* __restrict__ out){
  __shared__ __align__(16) char Al[2][8192];
  __shared__ __align__(16) char Bl[2][4096];
  const int tid = threadIdx.x, lane = tid & 63, wv = tid >> 6;
  const int l15 = lane & 15, l4 = lane >> 4;
  const int wr = wv >> 1, wc = wv & 1;
  const int n0 = blockIdx.x * 64;
  const int m0 = blockIdx.y * 128;

  f32x4 acc[4][2];
  #pragma unroll
  for (int i=0;i<4;i++)
    #pragma unroll
    for (int j=0;j<2;j++) acc[i][j] = (f32x4){0.f,0.f,0.f,0.f};

  const char *ga0, *ga1, *gbp;
  {
    int u = tid, c = u>>6, l = u&63;
    ga0 = (const char*)A + ((size_t)(m0 + c*16 + (l&15))*DM + (l>>4)*8)*2;
    gbp = (const char*)WoT + ((size_t)(n0 + c*16 + (l&15))*DM + (l>>4)*8)*2;
    u = tid + 256; c = u>>6; l = u&63;
    ga1 = (const char*)A + ((size_t)(m0 + c*16 + (l&15))*DM + (l>>4)*8)*2;
  }
  const int lo0 = tid*16, lo1 = tid*16 + 4096;

  auto compute = [&](const char* __restrict__ Ab, const char* __restrict__ Bb){
    short8_t av[4], bvv[2];
    #pragma unroll
    for (int i=0;i<4;i++) av[i]  = *(const short8_t*)(Ab + (wr*4+i)*1024 + lane*16);
    #pragma unroll
    for (int j=0;j<2;j++) bvv[j] = *(const short8_t*)(Bb + (wc*2+j)*1024 + lane*16);
    __builtin_amdgcn_s_setprio(1);
    #pragma unroll
    for (int i=0;i<4;i++)
      #pragma unroll
      for (int j=0;j<2;j++)
        acc[i][j] = __builtin_amdgcn_mfma_f32_16x16x32_bf16(av[i], bvv[j], acc[i][j], 0,0,0);
    __builtin_amdgcn_s_setprio(0);
  };

  const int NT = DM/32;
  uint4 Xa0,Xa1,Xb, Ya0,Ya1,Yb;
  Xa0=*(const uint4*)(ga0);     Xa1=*(const uint4*)(ga1);     Xb=*(const uint4*)(gbp);
  Ya0=*(const uint4*)(ga0+64);  Ya1=*(const uint4*)(ga1+64);  Yb=*(const uint4*)(gbp+64);
  *(uint4*)(Al[0]+lo0)=Xa0; *(uint4*)(Al[0]+lo1)=Xa1; *(uint4*)(Bl[0]+lo0)=Xb;
  Xa0=*(const uint4*)(ga0+128); Xa1=*(const uint4*)(ga1+128); Xb=*(const uint4*)(gbp+128);
  __syncthreads();

  for (int u=0; u<NT/2; ++u){
    compute(Al[0], Bl[0]);
    *(uint4*)(Al[1]+lo0)=Ya0; *(uint4*)(Al[1]+lo1)=Ya1; *(uint4*)(Bl[1]+lo0)=Yb;
    if (2*u+3 < NT){
      size_t o = (size_t)(2*u+3)*64;
      Ya0=*(const uint4*)(ga0+o); Ya1=*(const uint4*)(ga1+o); Yb=*(const uint4*)(gbp+o);
    }
    __syncthreads();
    compute(Al[1], Bl[1]);
    if (2*u+2 < NT){
      *(uint4*)(Al[0]+lo0)=Xa0; *(uint4*)(Al[0]+lo1)=Xa1; *(uint4*)(Bl[0]+lo0)=Xb;
      if (2*u+4 < NT){
        size_t o = (size_t)(2*u+4)*64;
        Xa0=*(const uint4*)(ga0+o); Xa1=*(const uint4*)(ga1+o); Xb=*(const uint4*)(gbp+o);
      }
    }
    __syncthreads();
  }

  #pragma unroll
  for (int i=0;i<4;i++)
    #pragma unroll
    for (int j=0;j<2;j++)
      #pragma unroll
      for (int jr=0;jr<4;jr++){
        int m = m0 + wr*64 + i*16 + l4*4 + jr;
        int n = n0 + wc*32 + j*16 + l15;
        out[(size_t)m*DM + n] = acc[i][j][jr] + bo[n];
      }
}

// ---------------- flash attention, 32x32 MFMA (R4 baseline) ----------------
// 4 waves x 32 q-rows = 128 q/block; KV tiles of 64; log2-domain online softmax,
// defer-max THR=8; sums via ones-MFMA; P distributed by cvt_pk + permlane32_swap.
__global__ __launch_bounds__(256, 2) void attn_fwd(const unsigned short* __restrict__ Qp,
    const unsigned short* __restrict__ Kp, const unsigned short* __restrict__ VTp,
    const unsigned long long* __restrict__ Mb, unsigned short* __restrict__ X){
  __shared__ __align__(16) char smem[32768];   // [K0,K1,V0,V1] 8KB each; epilogue reuses 16KB
  const int tid = threadIdx.x, lane = tid & 63, wv = tid >> 6;
  const int q31 = lane & 31, h = lane >> 5;
  const int bh = blockIdx.y, b = bh >> 4, hh = bh & 15;
  const int q0 = blockIdx.x * 128;
  const int qrow = q0 + wv*32 + q31;

  const unsigned short* Qb = Qp + ((size_t)bh*S + qrow)*HD;
  short8_t qf[4];
  #pragma unroll
  for (int ks=0;ks<4;ks++) qf[ks] = *(const short8_t*)(Qb + ks*16 + h*8);

  short8_t ones8;
  #pragma unroll
  for (int j2=0;j2<8;j2++) ones8[j2] = (short)0x3F80;

  f32x16 o0, o1, aS;
  #pragma unroll
  for (int r=0;r<16;r++){ o0[r]=0.f; o1[r]=0.f; aS[r]=0.f; }
  float mrun = -3.0e38f;

  const char* KsrcB = (const char*)(Kp + (size_t)bh*S*HD);
  const char* VsrcB = (const char*)(VTp + (size_t)bh*HD*S);
  const unsigned long long* mrow = Mb + ((size_t)b*S + qrow)*(S/64);

  // staging: K chunk c: kv = 32*(c>>2)+(l&31), d = (c&3)*16+(l>>5)*8; LDS = u*16
  const char* kg[2]; const char* vg[2]; int ldso[2];
  #pragma unroll
  for (int i=0;i<2;i++){
    int u = tid + i*256, c = u>>6, l = u&63;
    kg[i] = KsrcB + ((size_t)(32*(c>>2) + (l&31))*HD + (c&3)*16 + (l>>5)*8)*2;
    vg[i] = VsrcB + ((size_t)(32*(c>>2) + (l&31))*S  + (c&3)*16 + (l>>5)*8)*2;
    ldso[i] = u*16;
  }

  uint4 kr0 = *(const uint4*)kg[0], kr1 = *(const uint4*)kg[1];
  uint4 vr0 = *(const uint4*)vg[0], vr1 = *(const uint4*)vg[1];
  unsigned long long wnx = mrow[0];
  *(uint4*)(smem + ldso[0]) = kr0; *(uint4*)(smem + ldso[1]) = kr1;
  *(uint4*)(smem + 16384 + ldso[0]) = vr0; *(uint4*)(smem + 16384 + ldso[1]) = vr1;
  __syncthreads();

  const int NT = S/64;
  int pb = 0;
  for (int t=0; t<NT; ++t){
    unsigned long long wcur = wnx;
    if (t+1 < NT){
      kr0 = *(const uint4*)(kg[0] + (size_t)(t+1)*8192);
      kr1 = *(const uint4*)(kg[1] + (size_t)(t+1)*8192);
      vr0 = *(const uint4*)(vg[0] + (size_t)(t+1)*128);
      vr1 = *(const uint4*)(vg[1] + (size_t)(t+1)*128);
      wnx = mrow[t+1];
    }
    const char* kb = smem + pb*8192;
    const char* vb = smem + 16384 + pb*8192;

    f32x16 c0, c1;
    #pragma unroll
    for (int r=0;r<16;r++){ c0[r]=0.f; c1[r]=0.f; }
    __builtin_amdgcn_s_setprio(1);
    #pragma unroll
    for (int ks=0;ks<4;ks++){
      short8_t kf0 = *(const short8_t*)(kb + ks*1024 + lane*16);
      c0 = __builtin_amdgcn_mfma_f32_32x32x16_bf16(kf0, qf[ks], c0, 0,0,0);
      short8_t kf1 = *(const short8_t*)(kb + (4+ks)*1024 + lane*16);
      c1 = __builtin_amdgcn_mfma_f32_32x32x16_bf16(kf1, qf[ks], c1, 0,0,0);
    }
    __builtin_amdgcn_s_setprio(0);

    // max (log2 domain), defer-max THR=8
    float mf = c0[0];
    #pragma unroll
    for (int r=1;r<16;r++) mf = fmaxf(mf, c0[r]);
    #pragma unroll
    for (int r=0;r<16;r++) mf = fmaxf(mf, c1[r]);
    mf = fmaxf(mf, __shfl_xor(mf, 32));
    if (!__all(mf <= mrun + 8.0f)){
      float mnew = fmaxf(mrun, mf);
      float rs = ex2(mrun - mnew);
      mrun = mnew;
      #pragma unroll
      for (int r=0;r<16;r++){ o0[r]*=rs; o1[r]*=rs; }
      aS[0]*=rs;
    }

    // exp2 + bitmask zeroing
    unsigned long long wsh = wcur >> (4*h);
    unsigned mlo = (unsigned)wsh, mhi = (unsigned)(wsh >> 32);
    #pragma unroll
    for (int r=0;r<16;r++){
      const int bitc = (r&3) + 8*(r>>2);
      float e0 = ex2(c0[r] - mrun);
      float e1 = ex2(c1[r] - mrun);
      c0[r] = ((mlo >> bitc) & 1u) ? e0 : 0.f;
      c1[r] = ((mhi >> bitc) & 1u) ? e1 : 0.f;
    }

    // pack to bf16 pairs, redistribute into PV B-fragments via permlane32_swap
    unsigned w0[8], w1[8];
    #pragma unroll
    for (int m=0;m<8;m++){ w0[m] = pk2(c0[2*m], c0[2*m+1]); w1[m] = pk2(c1[2*m], c1[2*m+1]); }
    union Frag { short8_t s; unsigned w[4]; };
    Frag pf[4];
    { unsigned x=w0[0], y=w0[2]; pswap(x,y); pf[0].w[0]=x; pf[0].w[2]=y; }
    { unsigned x=w0[1], y=w0[3]; pswap(x,y); pf[0].w[1]=x; pf[0].w[3]=y; }
    { unsigned x=w0[4], y=w0[6]; pswap(x,y); pf[1].w[0]=x; pf[1].w[2]=y; }
    { unsigned x=w0[5], y=w0[7]; pswap(x,y); pf[1].w[1]=x; pf[1].w[3]=y; }
    { unsigned x=w1[0], y=w1[2]; pswap(x,y); pf[2].w[0]=x; pf[2].w[2]=y; }
    { unsigned x=w1[1], y=w1[3]; pswap(x,y); pf[2].w[1]=x; pf[2].w[3]=y; }
    { unsigned x=w1[4], y=w1[6]; pswap(x,y); pf[3].w[0]=x; pf[3].w[2]=y; }
    { unsigned x=w1[5], y=w1[7]; pswap(x,y); pf[3].w[1]=x; pf[3].w[3]=y; }

    __builtin_amdgcn_s_setprio(1);
    #pragma unroll
    for (int kvs=0;kvs<4;kvs++){
      aS = __builtin_amdgcn_mfma_f32_32x32x16_bf16(ones8, pf[kvs].s, aS, 0,0,0);
      short8_t vf0 = *(const short8_t*)(vb + kvs*1024 + lane*16);
      o0 = __builtin_amdgcn_mfma_f32_32x32x16_bf16(vf0, pf[kvs].s, o0, 0,0,0);
      short8_t vf1 = *(const short8_t*)(vb + (4+kvs)*1024 + lane*16);
      o1 = __builtin_amdgcn_mfma_f32_32x32x16_bf16(vf1, pf[kvs].s, o1, 0,0,0);
    }
    __builtin_amdgcn_s_setprio(0);

    if (t+1 < NT){
      char* kw = smem + (pb^1)*8192;
      char* vw = smem + 16384 + (pb^1)*8192;
      *(uint4*)(kw + ldso[0]) = kr0; *(uint4*)(kw + ldso[1]) = kr1;
      *(uint4*)(vw + ldso[0]) = vr0; *(uint4*)(vw + ldso[1]) = vr1;
    }
    __syncthreads();
    pb ^= 1;
  }

  // epilogue: normalize, stage rows in LDS (16B-slot XOR by row&7), coalesced store
  float inv = 1.0f / aS[0];
  const int ql = wv*32 + q31;
  #pragma unroll
  for (int m=0;m<8;m++){
    int d0 = ((2*m)&3) + 8*(m>>1) + 4*h;
    unsigned wa = pk2(o0[2*m]*inv, o0[2*m+1]*inv);
    *(unsigned*)(smem + ql*128 + (((d0>>3) ^ (ql&7))*16) + (d0&7)*2) = wa;
    int d1 = d0 + 32;
    unsigned wb2 = pk2(o1[2*m]*inv, o1[2*m+1]*inv);
    *(unsigned*)(smem + ql*128 + (((d1>>3) ^ (ql&7))*16) + (d1&7)*2) = wb2;
  }
  __syncthreads();
  #pragma unroll
  for (int it=0; it<4; it++){
    int u = it*256 + tid;
    int row = u>>3, cc = u&7;
    uint4 vvv = *(const uint4*)(smem + row*128 + cc*16);
    int g = cc ^ (row & 7);
    *(uint4*)(X + ((size_t)b*S + q0 + row)*DM + hh*HD + g*8) = vvv;
  }
}

// ---------------- launch ----------------
extern "C" void kernel_launch(void* const* d_in, const int* in_sizes, int n_in,
                              void* d_out, int out_size, void* d_ws, size_t ws_size,
                              hipStream_t stream){
  const float* query = (const float*)d_in[0];
  const float* key   = (const float*)d_in[1];
  const float* value = (const float*)d_in[2];
  const int*   mask  = (const int*)d_in[3];
  const float* Wq = (const float*)d_in[4];
  const float* bq = (const float*)d_in[5];
  const float* Wk = (const float*)d_in[6];
  const float* bk = (const float*)d_in[7];
  const float* Wv = (const float*)d_in[8];
  const float* bvp= (const float*)d_in[9];
  const float* Wo = (const float*)d_in[10];
  const float* bo = (const float*)d_in[11];

  const size_t NE = (size_t)NB*S*DM;       // 4194304
  const size_t WE = (size_t)DM*DM;         // 1048576
  const size_t ME = (size_t)NB*S*S;        // 8388608

  char* w = (char*)d_ws;
  unsigned short* qb  = (unsigned short*)w; w += NE*2;
  unsigned short* kb  = (unsigned short*)w; w += NE*2;
  unsigned short* vb  = (unsigned short*)w; w += NE*2;
  unsigned short* WT  = (unsigned short*)w; w += 3*WE*2;
  unsigned short* WoT = (unsigned short*)w; w += WE*2;
  unsigned short* m16 = (unsigned short*)w; w += (ME/16)*2;
  unsigned short* Qp  = (unsigned short*)w; w += NE*2;
  unsigned short* Kp  = (unsigned short*)w; w += NE*2;
  unsigned short* VTp = (unsigned short*)w; w += NE*2;
  unsigned short* xb  = (unsigned short*)w; w += NE*2;

  prep<<<12288, 256, 0, stream>>>(query, key, value, mask, Wq, Wk, Wv, Wo,
                                  qb, kb, vb, WT, WoT, m16);
  qkv_gemm<<<dim3(24,32), 256, 0, stream>>>(qb, kb, vb, WT, bq, bk, bvp, Qp, Kp, VTp);
  attn_fwd<<<dim3(S/128, NB*H), 256, 0, stream>>>(Qp, Kp, VTp,
                                  (const unsigned long long*)m16, xb);
  out_gemm<<<dim3(DM/64, (NB*S)/128), 256, 0, stream>>>(xb, WoT, bo, (float*)d_out);
}

// Round 7
// 276.668 us; speedup vs baseline: 1.5617x; 1.5617x over previous
//
#include <hip/hip_runtime.h>
#include <hip/hip_bf16.h>

#define H 16
#define S 2048
#define DM 1024
#define HD 64
#define NB 2
#define LOG2E 1.4426950408889634f

typedef __attribute__((ext_vector_type(8))) short short8_t;
typedef __attribute__((ext_vector_type(4))) float f32x4;
typedef __attribute__((ext_vector_type(16))) float f32x16;

static __device__ __forceinline__ unsigned short f2bf(float f){
  union { float f; unsigned u; } x; x.f = f;
  unsigned r = x.u + 0x7fffu + ((x.u >> 16) & 1u);
  return (unsigned short)(r >> 16);
}

static __device__ __forceinline__ unsigned pk2(float a, float b){
  union { __hip_bfloat16 h; unsigned short u; } x, y;
  x.h = __hip_bfloat16(a); y.h = __hip_bfloat16(b);
  return (unsigned)x.u | ((unsigned)y.u << 16);
}

static __device__ __forceinline__ float ex2(float x){
#if __has_builtin(__builtin_amdgcn_exp2f)
  return __builtin_amdgcn_exp2f(x);
#else
  return exp2f(x);
#endif
}

// swap upper 32 lanes of x with lower 32 lanes of y (CDNA4 v_permlane32_swap_b32)
static __device__ __forceinline__ void pswap(unsigned &x, unsigned &y){
#if defined(__gfx950__) || defined(__AMDGCN__)
  asm("v_permlane32_swap_b32 %0, %1" : "+v"(x), "+v"(y));
#else
  unsigned sx = (unsigned)__shfl_xor((int)x, 32);
  unsigned sy = (unsigned)__shfl_xor((int)y, 32);
  bool hi = (threadIdx.x & 63) >= 32;
  unsigned nx = hi ? sy : x;
  unsigned ny = hi ? y : sx;
  x = nx; y = ny;
#endif
}

// ---------------- prep: all conversions in one launch ----------------
__global__ __launch_bounds__(256) void prep(const float* __restrict__ q, const float* __restrict__ k,
    const float* __restrict__ v, const int* __restrict__ mask,
    const float* __restrict__ Wq, const float* __restrict__ Wk, const float* __restrict__ Wv,
    const float* __restrict__ Wo,
    unsigned short* __restrict__ qb, unsigned short* __restrict__ kb, unsigned short* __restrict__ vb,
    unsigned short* __restrict__ WT, unsigned short* __restrict__ WoT,
    unsigned short* __restrict__ m16){
  __shared__ float tt[32][33];
  const int bid = blockIdx.x, tid = threadIdx.x;
  if (bid < 6144){
    const int w = bid >> 11;
    const int blk = bid & 2047;
    const float* src = (w==0)? q : (w==1)? k : v;
    unsigned short* dst = (w==0)? qb : (w==1)? kb : vb;
    size_t i = ((size_t)blk*256 + tid)*8;
    float4 x = *(const float4*)(src + i);
    float4 y = *(const float4*)(src + i + 4);
    ushort4 o1{f2bf(x.x),f2bf(x.y),f2bf(x.z),f2bf(x.w)};
    ushort4 o2{f2bf(y.x),f2bf(y.y),f2bf(y.z),f2bf(y.w)};
    *(ushort4*)(dst+i) = o1; *(ushort4*)(dst+i+4) = o2;
  } else if (bid < 8192){
    size_t base = ((size_t)(bid-6144)*256 + tid)*16;
    unsigned u = 0;
    #pragma unroll
    for (int j2=0;j2<4;j2++){
      int4 mm = *(const int4*)(mask + base + j2*4);
      u |= (mm.x!=0 ? 1u:0u) << (j2*4);
      u |= (mm.y!=0 ? 1u:0u) << (j2*4+1);
      u |= (mm.z!=0 ? 1u:0u) << (j2*4+2);
      u |= (mm.w!=0 ? 1u:0u) << (j2*4+3);
    }
    m16[base>>4] = (unsigned short)u;
  } else {
    const int wb = bid - 8192;
    const int widx = wb >> 10, t = wb & 1023;
    const float* W = (widx==0)? Wq : (widx==1)? Wk : (widx==2)? Wv : Wo;
    unsigned short* dst = (widx<3)? (WT + (size_t)widx*DM*DM) : WoT;
    const int tx = tid & 31, ty = tid >> 5;
    const int r0 = (t >> 5) * 32, c0 = (t & 31) * 32;
    #pragma unroll
    for (int i2=0;i2<32;i2+=8) tt[ty+i2][tx] = W[(size_t)(r0+ty+i2)*DM + c0+tx];
    __syncthreads();
    #pragma unroll
    for (int i2=0;i2<32;i2+=8) dst[(size_t)(c0+ty+i2)*DM + r0+tx] = f2bf(tt[tx][ty+i2]);
  }
}

// ---------------- fused QKV GEMM: 2-deep reg pipeline + XCD-grouping swizzle ----------------
// 128x128 tile, BK=32, 4 waves (2x2). 768 blocks; swizzle co-locates the 8 n-blocks
// sharing one A-strip onto one XCD (A reads become L2 hits).
__global__ __launch_bounds__(256, 2) void qkv_gemm(
    const unsigned short* __restrict__ qb, const unsigned short* __restrict__ kb,
    const unsigned short* __restrict__ vb2, const unsigned short* __restrict__ WT,
    const float* __restrict__ bq, const float* __restrict__ bk, const float* __restrict__ bv,
    unsigned short* __restrict__ Qp, unsigned short* __restrict__ Kp, unsigned short* __restrict__ VTp){
  __shared__ __align__(16) char Al[2][8192];
  __shared__ __align__(16) char Bl[2][8192];
  const int tid = threadIdx.x, lane = tid & 63, wv = tid >> 6;
  const int l15 = lane & 15, l4 = lane >> 4;
  const int wr = wv >> 1, wc = wv & 1;

  // swizzle: pbid = xcd + 8*(gq*8 + n), group g = gq*8 + xcd = p*32 + m
  const int pbid = blockIdx.x + 24*blockIdx.y;
  const int xcd = pbid & 7, t2 = pbid >> 3;
  const int nn = t2 & 7, gq = t2 >> 3;         // gq in [0,12)
  const int g = gq*8 + xcd;                    // [0,96)
  const int p = g >> 5;                        // {0,1,2}
  const int m0 = (g & 31) * 128;
  const int n0 = nn * 128;
  const unsigned short* A = (p==0)? qb : (p==1)? kb : vb2;
  const unsigned short* Bt = WT + (size_t)(p*8 + nn) * 128 * DM;
  const float* bias = (p==0)? bq : (p==1)? bk : bv;
  const bool sw = (p==2);

  f32x4 acc[4][4];
  #pragma unroll
  for (int i=0;i<4;i++)
    #pragma unroll
    for (int j=0;j<4;j++) acc[i][j] = (f32x4){0.f,0.f,0.f,0.f};

  // unit u (c=u>>6, l=u&63): row = c*16 + (l&15), k8 = l>>4; LDS offset = u*16 (linear)
  const char *ga0, *ga1, *gb0, *gb1;
  {
    int u = tid, c = u>>6, l = u&63;
    ga0 = (const char*)A  + ((size_t)(m0 + c*16 + (l&15))*DM + (l>>4)*8)*2;
    gb0 = (const char*)Bt + ((size_t)(c*16 + (l&15))*DM + (l>>4)*8)*2;
    u = tid + 256; c = u>>6; l = u&63;
    ga1 = (const char*)A  + ((size_t)(m0 + c*16 + (l&15))*DM + (l>>4)*8)*2;
    gb1 = (const char*)Bt + ((size_t)(c*16 + (l&15))*DM + (l>>4)*8)*2;
  }
  const int lo0 = tid*16, lo1 = tid*16 + 4096;

  auto compute = [&](const char* __restrict__ Ab, const char* __restrict__ Bb){
    short8_t av[4], bvv[4];
    #pragma unroll
    for (int i=0;i<4;i++) av[i]  = *(const short8_t*)(Ab + (wr*4+i)*1024 + lane*16);
    #pragma unroll
    for (int j=0;j<4;j++) bvv[j] = *(const short8_t*)(Bb + (wc*4+j)*1024 + lane*16);
    __builtin_amdgcn_s_setprio(1);
    if (sw){
      #pragma unroll
      for (int i=0;i<4;i++)
        #pragma unroll
        for (int j=0;j<4;j++)
          acc[i][j] = __builtin_amdgcn_mfma_f32_16x16x32_bf16(bvv[j], av[i], acc[i][j], 0,0,0);
    } else {
      #pragma unroll
      for (int i=0;i<4;i++)
        #pragma unroll
        for (int j=0;j<4;j++)
          acc[i][j] = __builtin_amdgcn_mfma_f32_16x16x32_bf16(av[i], bvv[j], acc[i][j], 0,0,0);
    }
    __builtin_amdgcn_s_setprio(0);
  };

  const int NT = DM/32;   // 32
  uint4 Aa0,Aa1,Ab0,Ab1, Ba0,Ba1,Bb0,Bb1;
  Aa0=*(const uint4*)(ga0);     Aa1=*(const uint4*)(ga1);
  Ab0=*(const uint4*)(gb0);     Ab1=*(const uint4*)(gb1);
  Ba0=*(const uint4*)(ga0+64);  Ba1=*(const uint4*)(ga1+64);
  Bb0=*(const uint4*)(gb0+64);  Bb1=*(const uint4*)(gb1+64);
  *(uint4*)(Al[0]+lo0)=Aa0; *(uint4*)(Al[0]+lo1)=Aa1;
  *(uint4*)(Bl[0]+lo0)=Ab0; *(uint4*)(Bl[0]+lo1)=Ab1;
  Aa0=*(const uint4*)(ga0+128); Aa1=*(const uint4*)(ga1+128);
  Ab0=*(const uint4*)(gb0+128); Ab1=*(const uint4*)(gb1+128);
  __syncthreads();

  for (int u=0; u<NT/2; ++u){
    compute(Al[0], Bl[0]);
    *(uint4*)(Al[1]+lo0)=Ba0; *(uint4*)(Al[1]+lo1)=Ba1;
    *(uint4*)(Bl[1]+lo0)=Bb0; *(uint4*)(Bl[1]+lo1)=Bb1;
    if (2*u+3 < NT){
      size_t o = (size_t)(2*u+3)*64;
      Ba0=*(const uint4*)(ga0+o); Ba1=*(const uint4*)(ga1+o);
      Bb0=*(const uint4*)(gb0+o); Bb1=*(const uint4*)(gb1+o);
    }
    __syncthreads();
    compute(Al[1], Bl[1]);
    if (2*u+2 < NT){
      *(uint4*)(Al[0]+lo0)=Aa0; *(uint4*)(Al[0]+lo1)=Aa1;
      *(uint4*)(Bl[0]+lo0)=Ab0; *(uint4*)(Bl[0]+lo1)=Ab1;
      if (2*u+4 < NT){
        size_t o = (size_t)(2*u+4)*64;
        Aa0=*(const uint4*)(ga0+o); Aa1=*(const uint4*)(ga1+o);
        Ab0=*(const uint4*)(gb0+o); Ab1=*(const uint4*)(gb1+o);
      }
    }
    __syncthreads();
  }

  if (!sw){
    unsigned short* out = (p==0)? Qp : Kp;
    const float scl = (p==0)? 0.125f*LOG2E : 1.0f;
    #pragma unroll
    for (int i=0;i<4;i++)
      #pragma unroll
      for (int j=0;j<4;j++)
        #pragma unroll
        for (int jr=0;jr<4;jr++){
          int m = m0 + wr*64 + i*16 + l4*4 + jr;
          int n = n0 + wc*64 + j*16 + l15;
          float val = (acc[i][j][jr] + bias[n]) * scl;
          int b2 = m >> 11, s = m & (S-1), hh2 = n >> 6, d = n & 63;
          out[(((size_t)b2*H + hh2)*S + s)*HD + d] = f2bf(val);
        }
  } else {
    #pragma unroll
    for (int i=0;i<4;i++)
      #pragma unroll
      for (int j=0;j<4;j++)
        #pragma unroll
        for (int jr=0;jr<4;jr++){
          int n = n0 + wc*64 + j*16 + l4*4 + jr;
          int m = m0 + wr*64 + i*16 + l15;
          float val = acc[i][j][jr] + bias[n];
          int b2 = m >> 11, s = m & (S-1), hh2 = n >> 6, d = n & 63;
          VTp[(((size_t)b2*H + hh2)*HD + d)*S + s] = f2bf(val);
        }
  }
}

// ---------------- output GEMM: 128x64 tile, 2-deep reg pipeline + swizzle, fp32 out ----------------
__global__ __launch_bounds__(256, 2) void out_gemm(const unsigned short* __restrict__ A,
    const unsigned short* __restrict__ WoT, const float* __restrict__ bo, float* __restrict__ out){
  __shared__ __align__(16) char Al[2][8192];
  __shared__ __align__(16) char Bl[2][4096];
  const int tid = threadIdx.x, lane = tid & 63, wv = tid >> 6;
  const int l15 = lane & 15, l4 = lane >> 4;
  const int wr = wv >> 1, wc = wv & 1;

  // swizzle: 512 blocks; 16 n-blocks sharing an A-strip -> one XCD
  const int pbid = blockIdx.x + 16*blockIdx.y;
  const int xcd = pbid & 7, t2 = pbid >> 3;    // t2 in [0,64)
  const int nn = t2 & 15, mq = t2 >> 4;        // mq in [0,4)
  const int n0 = nn * 64;
  const int m0 = (mq*8 + xcd) * 128;

  f32x4 acc[4][2];
  #pragma unroll
  for (int i=0;i<4;i++)
    #pragma unroll
    for (int j=0;j<2;j++) acc[i][j] = (f32x4){0.f,0.f,0.f,0.f};

  const char *ga0, *ga1, *gbp;
  {
    int u = tid, c = u>>6, l = u&63;
    ga0 = (const char*)A + ((size_t)(m0 + c*16 + (l&15))*DM + (l>>4)*8)*2;
    gbp = (const char*)WoT + ((size_t)(n0 + c*16 + (l&15))*DM + (l>>4)*8)*2;
    u = tid + 256; c = u>>6; l = u&63;
    ga1 = (const char*)A + ((size_t)(m0 + c*16 + (l&15))*DM + (l>>4)*8)*2;
  }
  const int lo0 = tid*16, lo1 = tid*16 + 4096;

  auto compute = [&](const char* __restrict__ Ab, const char* __restrict__ Bb){
    short8_t av[4], bvv[2];
    #pragma unroll
    for (int i=0;i<4;i++) av[i]  = *(const short8_t*)(Ab + (wr*4+i)*1024 + lane*16);
    #pragma unroll
    for (int j=0;j<2;j++) bvv[j] = *(const short8_t*)(Bb + (wc*2+j)*1024 + lane*16);
    __builtin_amdgcn_s_setprio(1);
    #pragma unroll
    for (int i=0;i<4;i++)
      #pragma unroll
      for (int j=0;j<2;j++)
        acc[i][j] = __builtin_amdgcn_mfma_f32_16x16x32_bf16(av[i], bvv[j], acc[i][j], 0,0,0);
    __builtin_amdgcn_s_setprio(0);
  };

  const int NT = DM/32;
  uint4 Xa0,Xa1,Xb, Ya0,Ya1,Yb;
  Xa0=*(const uint4*)(ga0);     Xa1=*(const uint4*)(ga1);     Xb=*(const uint4*)(gbp);
  Ya0=*(const uint4*)(ga0+64);  Ya1=*(const uint4*)(ga1+64);  Yb=*(const uint4*)(gbp+64);
  *(uint4*)(Al[0]+lo0)=Xa0; *(uint4*)(Al[0]+lo1)=Xa1; *(uint4*)(Bl[0]+lo0)=Xb;
  Xa0=*(const uint4*)(ga0+128); Xa1=*(const uint4*)(ga1+128); Xb=*(const uint4*)(gbp+128);
  __syncthreads();

  for (int u=0; u<NT/2; ++u){
    compute(Al[0], Bl[0]);
    *(uint4*)(Al[1]+lo0)=Ya0; *(uint4*)(Al[1]+lo1)=Ya1; *(uint4*)(Bl[1]+lo0)=Yb;
    if (2*u+3 < NT){
      size_t o = (size_t)(2*u+3)*64;
      Ya0=*(const uint4*)(ga0+o); Ya1=*(const uint4*)(ga1+o); Yb=*(const uint4*)(gbp+o);
    }
    __syncthreads();
    compute(Al[1], Bl[1]);
    if (2*u+2 < NT){
      *(uint4*)(Al[0]+lo0)=Xa0; *(uint4*)(Al[0]+lo1)=Xa1; *(uint4*)(Bl[0]+lo0)=Xb;
      if (2*u+4 < NT){
        size_t o = (size_t)(2*u+4)*64;
        Xa0=*(const uint4*)(ga0+o); Xa1=*(const uint4*)(ga1+o); Xb=*(const uint4*)(gbp+o);
      }
    }
    __syncthreads();
  }

  #pragma unroll
  for (int i=0;i<4;i++)
    #pragma unroll
    for (int j=0;j<2;j++)
      #pragma unroll
      for (int jr=0;jr<4;jr++){
        int m = m0 + wr*64 + i*16 + l4*4 + jr;
        int n = n0 + wc*32 + j*16 + l15;
        out[(size_t)m*DM + n] = acc[i][j][jr] + bo[n];
      }
}

// ---------------- flash attention, 32x32 MFMA (R4 baseline, unchanged) ----------------
__global__ __launch_bounds__(256, 2) void attn_fwd(const unsigned short* __restrict__ Qp,
    const unsigned short* __restrict__ Kp, const unsigned short* __restrict__ VTp,
    const unsigned long long* __restrict__ Mb, unsigned short* __restrict__ X){
  __shared__ __align__(16) char smem[32768];
  const int tid = threadIdx.x, lane = tid & 63, wv = tid >> 6;
  const int q31 = lane & 31, h = lane >> 5;
  const int bh = blockIdx.y, b = bh >> 4, hh = bh & 15;
  const int q0 = blockIdx.x * 128;
  const int qrow = q0 + wv*32 + q31;

  const unsigned short* Qb = Qp + ((size_t)bh*S + qrow)*HD;
  short8_t qf[4];
  #pragma unroll
  for (int ks=0;ks<4;ks++) qf[ks] = *(const short8_t*)(Qb + ks*16 + h*8);

  short8_t ones8;
  #pragma unroll
  for (int j2=0;j2<8;j2++) ones8[j2] = (short)0x3F80;

  f32x16 o0, o1, aS;
  #pragma unroll
  for (int r=0;r<16;r++){ o0[r]=0.f; o1[r]=0.f; aS[r]=0.f; }
  float mrun = -3.0e38f;

  const char* KsrcB = (const char*)(Kp + (size_t)bh*S*HD);
  const char* VsrcB = (const char*)(VTp + (size_t)bh*HD*S);
  const unsigned long long* mrow = Mb + ((size_t)b*S + qrow)*(S/64);

  const char* kg[2]; const char* vg[2]; int ldso[2];
  #pragma unroll
  for (int i=0;i<2;i++){
    int u = tid + i*256, c = u>>6, l = u&63;
    kg[i] = KsrcB + ((size_t)(32*(c>>2) + (l&31))*HD + (c&3)*16 + (l>>5)*8)*2;
    vg[i] = VsrcB + ((size_t)(32*(c>>2) + (l&31))*S  + (c&3)*16 + (l>>5)*8)*2;
    ldso[i] = u*16;
  }

  uint4 kr0 = *(const uint4*)kg[0], kr1 = *(const uint4*)kg[1];
  uint4 vr0 = *(const uint4*)vg[0], vr1 = *(const uint4*)vg[1];
  unsigned long long wnx = mrow[0];
  *(uint4*)(smem + ldso[0]) = kr0; *(uint4*)(smem + ldso[1]) = kr1;
  *(uint4*)(smem + 16384 + ldso[0]) = vr0; *(uint4*)(smem + 16384 + ldso[1]) = vr1;
  __syncthreads();

  const int NT = S/64;
  int pb = 0;
  for (int t=0; t<NT; ++t){
    unsigned long long wcur = wnx;
    if (t+1 < NT){
      kr0 = *(const uint4*)(kg[0] + (size_t)(t+1)*8192);
      kr1 = *(const uint4*)(kg[1] + (size_t)(t+1)*8192);
      vr0 = *(const uint4*)(vg[0] + (size_t)(t+1)*128);
      vr1 = *(const uint4*)(vg[1] + (size_t)(t+1)*128);
      wnx = mrow[t+1];
    }
    const char* kb = smem + pb*8192;
    const char* vb = smem + 16384 + pb*8192;

    f32x16 c0, c1;
    #pragma unroll
    for (int r=0;r<16;r++){ c0[r]=0.f; c1[r]=0.f; }
    __builtin_amdgcn_s_setprio(1);
    #pragma unroll
    for (int ks=0;ks<4;ks++){
      short8_t kf0 = *(const short8_t*)(kb + ks*1024 + lane*16);
      c0 = __builtin_amdgcn_mfma_f32_32x32x16_bf16(kf0, qf[ks], c0, 0,0,0);
      short8_t kf1 = *(const short8_t*)(kb + (4+ks)*1024 + lane*16);
      c1 = __builtin_amdgcn_mfma_f32_32x32x16_bf16(kf1, qf[ks], c1, 0,0,0);
    }
    __builtin_amdgcn_s_setprio(0);

    float mf = c0[0];
    #pragma unroll
    for (int r=1;r<16;r++) mf = fmaxf(mf, c0[r]);
    #pragma unroll
    for (int r=0;r<16;r++) mf = fmaxf(mf, c1[r]);
    mf = fmaxf(mf, __shfl_xor(mf, 32));
    if (!__all(mf <= mrun + 8.0f)){
      float mnew = fmaxf(mrun, mf);
      float rs = ex2(mrun - mnew);
      mrun = mnew;
      #pragma unroll
      for (int r=0;r<16;r++){ o0[r]*=rs; o1[r]*=rs; }
      aS[0]*=rs;
    }

    unsigned long long wsh = wcur >> (4*h);
    unsigned mlo = (unsigned)wsh, mhi = (unsigned)(wsh >> 32);
    #pragma unroll
    for (int r=0;r<16;r++){
      const int bitc = (r&3) + 8*(r>>2);
      float e0 = ex2(c0[r] - mrun);
      float e1 = ex2(c1[r] - mrun);
      c0[r] = ((mlo >> bitc) & 1u) ? e0 : 0.f;
      c1[r] = ((mhi >> bitc) & 1u) ? e1 : 0.f;
    }

    unsigned w0[8], w1[8];
    #pragma unroll
    for (int m=0;m<8;m++){ w0[m] = pk2(c0[2*m], c0[2*m+1]); w1[m] = pk2(c1[2*m], c1[2*m+1]); }
    union Frag { short8_t s; unsigned w[4]; };
    Frag pf[4];
    { unsigned x=w0[0], y=w0[2]; pswap(x,y); pf[0].w[0]=x; pf[0].w[2]=y; }
    { unsigned x=w0[1], y=w0[3]; pswap(x,y); pf[0].w[1]=x; pf[0].w[3]=y; }
    { unsigned x=w0[4], y=w0[6]; pswap(x,y); pf[1].w[0]=x; pf[1].w[2]=y; }
    { unsigned x=w0[5], y=w0[7]; pswap(x,y); pf[1].w[1]=x; pf[1].w[3]=y; }
    { unsigned x=w1[0], y=w1[2]; pswap(x,y); pf[2].w[0]=x; pf[2].w[2]=y; }
    { unsigned x=w1[1], y=w1[3]; pswap(x,y); pf[2].w[1]=x; pf[2].w[3]=y; }
    { unsigned x=w1[4], y=w1[6]; pswap(x,y); pf[3].w[0]=x; pf[3].w[2]=y; }
    { unsigned x=w1[5], y=w1[7]; pswap(x,y); pf[3].w[1]=x; pf[3].w[3]=y; }

    __builtin_amdgcn_s_setprio(1);
    #pragma unroll
    for (int kvs=0;kvs<4;kvs++){
      aS = __builtin_amdgcn_mfma_f32_32x32x16_bf16(ones8, pf[kvs].s, aS, 0,0,0);
      short8_t vf0 = *(const short8_t*)(vb + kvs*1024 + lane*16);
      o0 = __builtin_amdgcn_mfma_f32_32x32x16_bf16(vf0, pf[kvs].s, o0, 0,0,0);
      short8_t vf1 = *(const short8_t*)(vb + (4+kvs)*1024 + lane*16);
      o1 = __builtin_amdgcn_mfma_f32_32x32x16_bf16(vf1, pf[kvs].s, o1, 0,0,0);
    }
    __builtin_amdgcn_s_setprio(0);

    if (t+1 < NT){
      char* kw = smem + (pb^1)*8192;
      char* vw = smem + 16384 + (pb^1)*8192;
      *(uint4*)(kw + ldso[0]) = kr0; *(uint4*)(kw + ldso[1]) = kr1;
      *(uint4*)(vw + ldso[0]) = vr0; *(uint4*)(vw + ldso[1]) = vr1;
    }
    __syncthreads();
    pb ^= 1;
  }

  float inv = 1.0f / aS[0];
  const int ql = wv*32 + q31;
  #pragma unroll
  for (int m=0;m<8;m++){
    int d0 = ((2*m)&3) + 8*(m>>1) + 4*h;
    unsigned wa = pk2(o0[2*m]*inv, o0[2*m+1]*inv);
    *(unsigned*)(smem + ql*128 + (((d0>>3) ^ (ql&7))*16) + (d0&7)*2) = wa;
    int d1 = d0 + 32;
    unsigned wb2 = pk2(o1[2*m]*inv, o1[2*m+1]*inv);
    *(unsigned*)(smem + ql*128 + (((d1>>3) ^ (ql&7))*16) + (d1&7)*2) = wb2;
  }
  __syncthreads();
  #pragma unroll
  for (int it=0; it<4; it++){
    int u = it*256 + tid;
    int row = u>>3, cc = u&7;
    uint4 vvv = *(const uint4*)(smem + row*128 + cc*16);
    int g = cc ^ (row & 7);
    *(uint4*)(X + ((size_t)b*S + q0 + row)*DM + hh*HD + g*8) = vvv;
  }
}

// ---------------- launch ----------------
extern "C" void kernel_launch(void* const* d_in, const int* in_sizes, int n_in,
                              void* d_out, int out_size, void* d_ws, size_t ws_size,
                              hipStream_t stream){
  const float* query = (const float*)d_in[0];
  const float* key   = (const float*)d_in[1];
  const float* value = (const float*)d_in[2];
  const int*   mask  = (const int*)d_in[3];
  const float* Wq = (const float*)d_in[4];
  const float* bq = (const float*)d_in[5];
  const float* Wk = (const float*)d_in[6];
  const float* bk = (const float*)d_in[7];
  const float* Wv = (const float*)d_in[8];
  const float* bvp= (const float*)d_in[9];
  const float* Wo = (const float*)d_in[10];
  const float* bo = (const float*)d_in[11];

  const size_t NE = (size_t)NB*S*DM;       // 4194304
  const size_t WE = (size_t)DM*DM;         // 1048576
  const size_t ME = (size_t)NB*S*S;        // 8388608

  char* w = (char*)d_ws;
  unsigned short* qb  = (unsigned short*)w; w += NE*2;
  unsigned short* kb  = (unsigned short*)w; w += NE*2;
  unsigned short* vb  = (unsigned short*)w; w += NE*2;
  unsigned short* WT  = (unsigned short*)w; w += 3*WE*2;
  unsigned short* WoT = (unsigned short*)w; w += WE*2;
  unsigned short* m16 = (unsigned short*)w; w += (ME/16)*2;
  unsigned short* Qp  = (unsigned short*)w; w += NE*2;
  unsigned short* Kp  = (unsigned short*)w; w += NE*2;
  unsigned short* VTp = (unsigned short*)w; w += NE*2;
  unsigned short* xb  = (unsigned short*)w; w += NE*2;

  prep<<<12288, 256, 0, stream>>>(query, key, value, mask, Wq, Wk, Wv, Wo,
                                  qb, kb, vb, WT, WoT, m16);
  qkv_gemm<<<dim3(24,32), 256, 0, stream>>>(qb, kb, vb, WT, bq, bk, bvp, Qp, Kp, VTp);
  attn_fwd<<<dim3(S/128, NB*H), 256, 0, stream>>>(Qp, Kp, VTp,
                                  (const unsigned long long*)m16, xb);
  out_gemm<<<dim3(DM/64, (NB*S)/128), 256, 0, stream>>>(xb, WoT, bo, (float*)d_out);
}